// Round 1
// baseline (183.198 us; speedup 1.0000x reference)
//
#include <hip/hip_runtime.h>
#include <hip/hip_bf16.h>

#define B_N 4096
#define D_K 2048

typedef __attribute__((ext_vector_type(8))) short bf16x8;
typedef __attribute__((ext_vector_type(4))) float f32x4;

__device__ __forceinline__ unsigned short f2bf(float f) {
    union { __hip_bfloat16 h; unsigned short u; } cv;
    cv.h = __float2bfloat16(f);
    return cv.u;
}

// ---------------- Kernel 1: inverse L2 norms of each row ----------------
__global__ __launch_bounds__(256) void knorm(const float* __restrict__ C,
                                             const float* __restrict__ S,
                                             float* __restrict__ invc,
                                             float* __restrict__ invs) {
    int b = blockIdx.x;                 // 0..8191: first 4096 = cond rows, rest = sol rows
    const float* X = (b < B_N) ? (C + (size_t)b * D_K)
                               : (S + (size_t)(b - B_N) * D_K);
    int tid = threadIdx.x;
    float ss = 0.f;
    #pragma unroll
    for (int i = tid * 4; i < D_K; i += 256 * 4) {
        float4 v = *(const float4*)(X + i);
        ss += v.x * v.x + v.y * v.y + v.z * v.z + v.w * v.w;
    }
    #pragma unroll
    for (int off = 1; off < 64; off <<= 1) ss += __shfl_xor(ss, off, 64);
    __shared__ float wsum[4];
    if ((tid & 63) == 0) wsum[tid >> 6] = ss;
    __syncthreads();
    if (tid == 0) {
        float t = wsum[0] + wsum[1] + wsum[2] + wsum[3];
        float n = sqrtf(t);
        float inv = 1.f / fmaxf(n, 1e-12f);
        if (b < B_N) invc[b] = inv; else invs[b - B_N] = inv;
    }
}

// ---------------- Kernel 2: fused GEMM + relu*scale + exp + row/col partial sums ----------------
#define BM 128
#define BN 128
#define BK 32
#define LDSP 40   // padded row stride in bf16 elems (80 B: 16B-aligned, only free 2-way conflicts)

__global__ __launch_bounds__(256) void kgemm(const float* __restrict__ Cf,
                                             const float* __restrict__ Sf,
                                             const float* __restrict__ invc,
                                             const float* __restrict__ invs,
                                             const float* __restrict__ temp,
                                             float* __restrict__ rowsum,
                                             float* __restrict__ colsum,
                                             float* __restrict__ diag) {
    __shared__ unsigned short As[BM][LDSP];
    __shared__ unsigned short Bs[BN][LDSP];

    int tid  = threadIdx.x;
    int lane = tid & 63;
    int wid  = tid >> 6;
    int wr   = wid >> 1;      // 0..1
    int wc   = wid & 1;       // 0..1
    int brow = blockIdx.x * BM;
    int bcol = blockIdx.y * BN;

    // staging decomposition: 256 threads -> 32 rows x 8 col-groups (float4 each), 4 iters
    int sr = tid >> 3;         // 0..31
    int sc = (tid & 7) * 4;    // 0,4,...,28

    float ia[4], ib[4];
    #pragma unroll
    for (int it = 0; it < 4; ++it) {
        ia[it] = invc[brow + sr + it * 32];
        ib[it] = invs[bcol + sr + it * 32];
    }

    f32x4 acc[4][4];
    #pragma unroll
    for (int m = 0; m < 4; ++m)
        #pragma unroll
        for (int n = 0; n < 4; ++n)
            acc[m][n] = (f32x4){0.f, 0.f, 0.f, 0.f};

    for (int k0 = 0; k0 < D_K; k0 += BK) {
        #pragma unroll
        for (int it = 0; it < 4; ++it) {
            int r = sr + it * 32;
            float4 va = *(const float4*)(Cf + (size_t)(brow + r) * D_K + k0 + sc);
            float4 vb = *(const float4*)(Sf + (size_t)(bcol + r) * D_K + k0 + sc);
            ushort4 wa, wb;
            wa.x = f2bf(va.x * ia[it]); wa.y = f2bf(va.y * ia[it]);
            wa.z = f2bf(va.z * ia[it]); wa.w = f2bf(va.w * ia[it]);
            wb.x = f2bf(vb.x * ib[it]); wb.y = f2bf(vb.y * ib[it]);
            wb.z = f2bf(vb.z * ib[it]); wb.w = f2bf(vb.w * ib[it]);
            *(ushort4*)&As[r][sc] = wa;
            *(ushort4*)&Bs[r][sc] = wb;
        }
        __syncthreads();

        int ar = wr * 64 + (lane & 15);
        int bc = wc * 64 + (lane & 15);
        int kg = (lane >> 4) * 8;
        bf16x8 af[4], bg[4];
        #pragma unroll
        for (int m = 0; m < 4; ++m) af[m] = *(const bf16x8*)&As[ar + m * 16][kg];
        #pragma unroll
        for (int n = 0; n < 4; ++n) bg[n] = *(const bf16x8*)&Bs[bc + n * 16][kg];

        #pragma unroll
        for (int m = 0; m < 4; ++m)
            #pragma unroll
            for (int n = 0; n < 4; ++n)
                acc[m][n] = __builtin_amdgcn_mfma_f32_16x16x32_bf16(af[m], bg[n], acc[m][n], 0, 0, 0);
        __syncthreads();
    }

    // ------- epilogue: relu * e^t, shifted exp, partial row/col sums, diag -------
    float scale = expf(temp[0]);     // also used as the logsumexp shift M
    int rbase = brow + wr * 64;                   // + m*16 + rj + j  -> global row
    int cbase = bcol + wc * 64 + (lane & 15);     // + n*16          -> global col
    int rj = (lane >> 4) * 4;

    float rs[4][4];   // per-lane partial row sums, [m][j]
    float cs[4];      // per-lane partial col sums, [n]
    #pragma unroll
    for (int m = 0; m < 4; ++m)
        #pragma unroll
        for (int j = 0; j < 4; ++j) rs[m][j] = 0.f;
    #pragma unroll
    for (int n = 0; n < 4; ++n) cs[n] = 0.f;

    #pragma unroll
    for (int m = 0; m < 4; ++m) {
        #pragma unroll
        for (int n = 0; n < 4; ++n) {
            #pragma unroll
            for (int j = 0; j < 4; ++j) {
                float sim = acc[m][n][j];
                float v = fmaxf(sim, 0.f) * scale;
                int gr = rbase + m * 16 + rj + j;
                int gc = cbase + n * 16;
                if (gr == gc) diag[gr] = v;     // each diagonal elem owned by exactly one block
                float p = expf(v - scale);      // shift M = scale (v <= ~scale)
                rs[m][j] += p;
                cs[n]    += p;
            }
        }
    }

    // row sums: reduce across the 16 lanes sharing (lane>>4, j)
    #pragma unroll
    for (int m = 0; m < 4; ++m) {
        #pragma unroll
        for (int j = 0; j < 4; ++j) {
            float v = rs[m][j];
            v += __shfl_xor(v, 1, 64);
            v += __shfl_xor(v, 2, 64);
            v += __shfl_xor(v, 4, 64);
            v += __shfl_xor(v, 8, 64);
            if ((lane & 15) == 0)
                atomicAdd(&rowsum[rbase + m * 16 + rj + j], v);
        }
    }
    // col sums: reduce across lane-groups {x, x+16, x+32, x+48}
    #pragma unroll
    for (int n = 0; n < 4; ++n) {
        float v = cs[n];
        v += __shfl_xor(v, 16, 64);
        v += __shfl_xor(v, 32, 64);
        if (lane < 16)
            atomicAdd(&colsum[cbase + n * 16], v);
    }
}

// ---------------- Kernel 3: final reduction to scalar loss ----------------
__global__ __launch_bounds__(256) void kfinal(const float* __restrict__ rowsum,
                                              const float* __restrict__ colsum,
                                              const float* __restrict__ diag,
                                              const float* __restrict__ temp,
                                              float* __restrict__ out) {
    int tid = threadIdx.x;
    float M = expf(temp[0]);
    float acc = 0.f;
    for (int i = tid; i < B_N; i += 256) {
        // (lse_row - diag) + (lse_col - diag), lse = M + log(sum exp(. - M))
        acc += logf(rowsum[i]) + logf(colsum[i]) + 2.f * M - 2.f * diag[i];
    }
    #pragma unroll
    for (int off = 1; off < 64; off <<= 1) acc += __shfl_xor(acc, off, 64);
    __shared__ float wsum[4];
    if ((tid & 63) == 0) wsum[tid >> 6] = acc;
    __syncthreads();
    if (tid == 0) {
        float t = wsum[0] + wsum[1] + wsum[2] + wsum[3];
        out[0] = t * (0.5f / (float)B_N);
    }
}

extern "C" void kernel_launch(void* const* d_in, const int* in_sizes, int n_in,
                              void* d_out, int out_size, void* d_ws, size_t ws_size,
                              hipStream_t stream) {
    const float* Cf   = (const float*)d_in[0];
    const float* Sf   = (const float*)d_in[1];
    const float* temp = (const float*)d_in[2];

    float* ws     = (float*)d_ws;
    float* invc   = ws;             // 4096
    float* invs   = ws + 4096;      // 4096
    float* rowsum = ws + 8192;      // 4096
    float* colsum = ws + 12288;     // 4096
    float* diag   = ws + 16384;     // 4096

    // zero the accumulators (harness poisons ws with 0xAA and never re-poisons)
    hipMemsetAsync(rowsum, 0, 2 * B_N * sizeof(float), stream);

    knorm<<<2 * B_N / 1, 256, 0, stream>>>(Cf, Sf, invc, invs);
    // note: grid = 8192 blocks (4096 cond rows + 4096 sol rows)

    dim3 grid(B_N / BM, B_N / BN);
    kgemm<<<grid, 256, 0, stream>>>(Cf, Sf, invc, invs, temp, rowsum, colsum, diag);

    kfinal<<<1, 256, 0, stream>>>(rowsum, colsum, diag, temp, (float*)d_out);
}

// Round 2
// 130.013 us; speedup vs baseline: 1.4091x; 1.4091x over previous
//
#include <hip/hip_runtime.h>
#include <hip/hip_bf16.h>

#define B_N 4096
#define D_K 2048

typedef __attribute__((ext_vector_type(8))) short bf16x8;
typedef __attribute__((ext_vector_type(4))) float f32x4;

__device__ __forceinline__ unsigned short f2bf(float f) {
    union { __hip_bfloat16 h; unsigned short u; } cv;
    cv.h = __float2bfloat16(f);
    return cv.u;
}

__device__ __forceinline__ void gload_lds16(const unsigned short* g, unsigned short* l) {
    __builtin_amdgcn_global_load_lds(
        (const __attribute__((address_space(1))) unsigned int*)g,
        (__attribute__((address_space(3))) unsigned int*)l,
        16, 0, 0);
}

// ---------------- Kernel 1 (fast path): row L2-normalize -> bf16 ----------------
__global__ __launch_bounds__(256) void knorm2(const float* __restrict__ C,
                                              const float* __restrict__ S,
                                              unsigned short* __restrict__ Cb,
                                              unsigned short* __restrict__ Sb) {
    int b = blockIdx.x;            // 0..8191
    const float* X;
    unsigned short* Y;
    if (b < B_N) { X = C + (size_t)b * D_K; Y = Cb + (size_t)b * D_K; }
    else         { X = S + (size_t)(b - B_N) * D_K; Y = Sb + (size_t)(b - B_N) * D_K; }
    int tid = threadIdx.x;

    // each thread owns 8 contiguous floats
    float4 v0 = ((const float4*)X)[tid * 2];
    float4 v1 = ((const float4*)X)[tid * 2 + 1];
    float ss = v0.x*v0.x + v0.y*v0.y + v0.z*v0.z + v0.w*v0.w
             + v1.x*v1.x + v1.y*v1.y + v1.z*v1.z + v1.w*v1.w;
    #pragma unroll
    for (int off = 1; off < 64; off <<= 1) ss += __shfl_xor(ss, off, 64);
    __shared__ float wsum[4];
    if ((tid & 63) == 0) wsum[tid >> 6] = ss;
    __syncthreads();
    float tot = wsum[0] + wsum[1] + wsum[2] + wsum[3];
    float inv = 1.f / fmaxf(sqrtf(tot), 1e-12f);

    bf16x8 o;
    o[0] = (short)f2bf(v0.x * inv); o[1] = (short)f2bf(v0.y * inv);
    o[2] = (short)f2bf(v0.z * inv); o[3] = (short)f2bf(v0.w * inv);
    o[4] = (short)f2bf(v1.x * inv); o[5] = (short)f2bf(v1.y * inv);
    o[6] = (short)f2bf(v1.z * inv); o[7] = (short)f2bf(v1.w * inv);
    *(bf16x8*)(Y + tid * 8) = o;
}

// ---------------- Kernel 2 (fast path): m97-structure bf16 GEMM + fused epilogue ----------------
#define BM 128
#define BN 128
#define BK 32

__global__ __launch_bounds__(256) void kgemm_bf(const unsigned short* __restrict__ Ab,
                                                const unsigned short* __restrict__ Bb,
                                                const float* __restrict__ temp,
                                                float* __restrict__ rowsum,
                                                float* __restrict__ colsum,
                                                float* __restrict__ diag) {
    __shared__ __align__(16) unsigned short As[BM * BK];   // linear, no pad (global_load_lds)
    __shared__ __align__(16) unsigned short Bs[BN * BK];

    int tid  = threadIdx.x;
    int lane = tid & 63;
    int wid  = tid >> 6;
    int wr   = wid >> 1;
    int wc   = wid & 1;
    int brow = blockIdx.x * BM;
    int bcol = blockIdx.y * BN;

    // staging: thread t owns 16B = 8 bf16 at tile elem offset t*8
    int trow = tid >> 2;          // 0..63
    int tcol = (tid & 3) * 8;     // 0,8,16,24
    const unsigned short* gA = Ab + (size_t)(brow + trow) * D_K + tcol;
    const unsigned short* gB = Bb + (size_t)(bcol + trow) * D_K + tcol;
    unsigned short* lA0 = &As[tid * 8];
    unsigned short* lA1 = &As[2048 + tid * 8];
    unsigned short* lB0 = &Bs[tid * 8];
    unsigned short* lB1 = &Bs[2048 + tid * 8];

    f32x4 acc[4][4];
    #pragma unroll
    for (int m = 0; m < 4; ++m)
        #pragma unroll
        for (int n = 0; n < 4; ++n)
            acc[m][n] = (f32x4){0.f, 0.f, 0.f, 0.f};

    const int frow = lane & 15;
    const int kg   = (lane >> 4) * 8;

    for (int k0 = 0; k0 < D_K; k0 += BK) {
        gload_lds16(gA + k0, lA0);
        gload_lds16(gA + (size_t)64 * D_K + k0, lA1);
        gload_lds16(gB + k0, lB0);
        gload_lds16(gB + (size_t)64 * D_K + k0, lB1);
        __syncthreads();   // compiler emits vmcnt(0) drain before barrier

        bf16x8 af[4], bg[4];
        #pragma unroll
        for (int m = 0; m < 4; ++m)
            af[m] = *(const bf16x8*)&As[(wr * 64 + m * 16 + frow) * BK + kg];
        #pragma unroll
        for (int n = 0; n < 4; ++n)
            bg[n] = *(const bf16x8*)&Bs[(wc * 64 + n * 16 + frow) * BK + kg];

        #pragma unroll
        for (int m = 0; m < 4; ++m)
            #pragma unroll
            for (int n = 0; n < 4; ++n)
                acc[m][n] = __builtin_amdgcn_mfma_f32_16x16x32_bf16(af[m], bg[n], acc[m][n], 0, 0, 0);
        __syncthreads();
    }

    // ------- epilogue: relu * e^t, shifted exp, partial row/col sums, diag -------
    float scale = expf(temp[0]);
    int rbase = brow + wr * 64;
    int cbase = bcol + wc * 64 + (lane & 15);
    int rj = (lane >> 4) * 4;

    float rs[4][4];
    float cs[4];
    #pragma unroll
    for (int m = 0; m < 4; ++m)
        #pragma unroll
        for (int j = 0; j < 4; ++j) rs[m][j] = 0.f;
    #pragma unroll
    for (int n = 0; n < 4; ++n) cs[n] = 0.f;

    #pragma unroll
    for (int m = 0; m < 4; ++m) {
        #pragma unroll
        for (int n = 0; n < 4; ++n) {
            #pragma unroll
            for (int j = 0; j < 4; ++j) {
                float sim = acc[m][n][j];
                float v = fmaxf(sim, 0.f) * scale;
                int gr = rbase + m * 16 + rj + j;
                int gc = cbase + n * 16;
                if (gr == gc) diag[gr] = v;
                float p = expf(v - scale);
                rs[m][j] += p;
                cs[n]    += p;
            }
        }
    }

    #pragma unroll
    for (int m = 0; m < 4; ++m) {
        #pragma unroll
        for (int j = 0; j < 4; ++j) {
            float v = rs[m][j];
            v += __shfl_xor(v, 1, 64);
            v += __shfl_xor(v, 2, 64);
            v += __shfl_xor(v, 4, 64);
            v += __shfl_xor(v, 8, 64);
            if ((lane & 15) == 0)
                atomicAdd(&rowsum[rbase + m * 16 + rj + j], v);
        }
    }
    #pragma unroll
    for (int n = 0; n < 4; ++n) {
        float v = cs[n];
        v += __shfl_xor(v, 16, 64);
        v += __shfl_xor(v, 32, 64);
        if (lane < 16)
            atomicAdd(&colsum[cbase + n * 16], v);
    }
}

// ---------------- Kernel 3: final reduction to scalar loss ----------------
__global__ __launch_bounds__(256) void kfinal(const float* __restrict__ rowsum,
                                              const float* __restrict__ colsum,
                                              const float* __restrict__ diag,
                                              const float* __restrict__ temp,
                                              float* __restrict__ out) {
    int tid = threadIdx.x;
    float M = expf(temp[0]);
    float acc = 0.f;
    for (int i = tid; i < B_N; i += 256) {
        acc += logf(rowsum[i]) + logf(colsum[i]) + 2.f * M - 2.f * diag[i];
    }
    #pragma unroll
    for (int off = 1; off < 64; off <<= 1) acc += __shfl_xor(acc, off, 64);
    __shared__ float wsum[4];
    if ((tid & 63) == 0) wsum[tid >> 6] = acc;
    __syncthreads();
    if (tid == 0) {
        float t = wsum[0] + wsum[1] + wsum[2] + wsum[3];
        out[0] = t * (0.5f / (float)B_N);
    }
}

// ================= Fallback path (round-1, used only if ws too small) =================
__global__ __launch_bounds__(256) void knorm(const float* __restrict__ C,
                                             const float* __restrict__ S,
                                             float* __restrict__ invc,
                                             float* __restrict__ invs) {
    int b = blockIdx.x;
    const float* X = (b < B_N) ? (C + (size_t)b * D_K)
                               : (S + (size_t)(b - B_N) * D_K);
    int tid = threadIdx.x;
    float ss = 0.f;
    #pragma unroll
    for (int i = tid * 4; i < D_K; i += 256 * 4) {
        float4 v = *(const float4*)(X + i);
        ss += v.x * v.x + v.y * v.y + v.z * v.z + v.w * v.w;
    }
    #pragma unroll
    for (int off = 1; off < 64; off <<= 1) ss += __shfl_xor(ss, off, 64);
    __shared__ float wsum[4];
    if ((tid & 63) == 0) wsum[tid >> 6] = ss;
    __syncthreads();
    if (tid == 0) {
        float t = wsum[0] + wsum[1] + wsum[2] + wsum[3];
        float inv = 1.f / fmaxf(sqrtf(t), 1e-12f);
        if (b < B_N) invc[b] = inv; else invs[b - B_N] = inv;
    }
}

#define LDSP 40
__global__ __launch_bounds__(256) void kgemm_f32(const float* __restrict__ Cf,
                                                 const float* __restrict__ Sf,
                                                 const float* __restrict__ invc,
                                                 const float* __restrict__ invs,
                                                 const float* __restrict__ temp,
                                                 float* __restrict__ rowsum,
                                                 float* __restrict__ colsum,
                                                 float* __restrict__ diag) {
    __shared__ unsigned short As[BM][LDSP];
    __shared__ unsigned short Bs[BN][LDSP];
    int tid = threadIdx.x, lane = tid & 63, wid = tid >> 6;
    int wr = wid >> 1, wc = wid & 1;
    int brow = blockIdx.x * BM, bcol = blockIdx.y * BN;
    int sr = tid >> 3, sc = (tid & 7) * 4;
    float ia[4], ib[4];
    #pragma unroll
    for (int it = 0; it < 4; ++it) {
        ia[it] = invc[brow + sr + it * 32];
        ib[it] = invs[bcol + sr + it * 32];
    }
    f32x4 acc[4][4];
    #pragma unroll
    for (int m = 0; m < 4; ++m)
        #pragma unroll
        for (int n = 0; n < 4; ++n) acc[m][n] = (f32x4){0.f,0.f,0.f,0.f};
    for (int k0 = 0; k0 < D_K; k0 += BK) {
        #pragma unroll
        for (int it = 0; it < 4; ++it) {
            int r = sr + it * 32;
            float4 va = *(const float4*)(Cf + (size_t)(brow + r) * D_K + k0 + sc);
            float4 vb = *(const float4*)(Sf + (size_t)(bcol + r) * D_K + k0 + sc);
            ushort4 wa, wb;
            wa.x = f2bf(va.x * ia[it]); wa.y = f2bf(va.y * ia[it]);
            wa.z = f2bf(va.z * ia[it]); wa.w = f2bf(va.w * ia[it]);
            wb.x = f2bf(vb.x * ib[it]); wb.y = f2bf(vb.y * ib[it]);
            wb.z = f2bf(vb.z * ib[it]); wb.w = f2bf(vb.w * ib[it]);
            *(ushort4*)&As[r][sc] = wa;
            *(ushort4*)&Bs[r][sc] = wb;
        }
        __syncthreads();
        int ar = wr * 64 + (lane & 15);
        int bc = wc * 64 + (lane & 15);
        int kg = (lane >> 4) * 8;
        bf16x8 af[4], bg[4];
        #pragma unroll
        for (int m = 0; m < 4; ++m) af[m] = *(const bf16x8*)&As[ar + m * 16][kg];
        #pragma unroll
        for (int n = 0; n < 4; ++n) bg[n] = *(const bf16x8*)&Bs[bc + n * 16][kg];
        #pragma unroll
        for (int m = 0; m < 4; ++m)
            #pragma unroll
            for (int n = 0; n < 4; ++n)
                acc[m][n] = __builtin_amdgcn_mfma_f32_16x16x32_bf16(af[m], bg[n], acc[m][n], 0, 0, 0);
        __syncthreads();
    }
    float scale = expf(temp[0]);
    int rbase = brow + wr * 64;
    int cbase = bcol + wc * 64 + (lane & 15);
    int rj = (lane >> 4) * 4;
    float rs[4][4], cs[4];
    #pragma unroll
    for (int m = 0; m < 4; ++m)
        #pragma unroll
        for (int j = 0; j < 4; ++j) rs[m][j] = 0.f;
    #pragma unroll
    for (int n = 0; n < 4; ++n) cs[n] = 0.f;
    #pragma unroll
    for (int m = 0; m < 4; ++m)
        #pragma unroll
        for (int n = 0; n < 4; ++n)
            #pragma unroll
            for (int j = 0; j < 4; ++j) {
                float v = fmaxf(acc[m][n][j], 0.f) * scale;
                int gr = rbase + m * 16 + rj + j;
                int gc = cbase + n * 16;
                if (gr == gc) diag[gr] = v;
                float p = expf(v - scale);
                rs[m][j] += p;
                cs[n] += p;
            }
    #pragma unroll
    for (int m = 0; m < 4; ++m)
        #pragma unroll
        for (int j = 0; j < 4; ++j) {
            float v = rs[m][j];
            v += __shfl_xor(v, 1, 64);
            v += __shfl_xor(v, 2, 64);
            v += __shfl_xor(v, 4, 64);
            v += __shfl_xor(v, 8, 64);
            if ((lane & 15) == 0) atomicAdd(&rowsum[rbase + m * 16 + rj + j], v);
        }
    #pragma unroll
    for (int n = 0; n < 4; ++n) {
        float v = cs[n];
        v += __shfl_xor(v, 16, 64);
        v += __shfl_xor(v, 32, 64);
        if (lane < 16) atomicAdd(&colsum[cbase + n * 16], v);
    }
}

extern "C" void kernel_launch(void* const* d_in, const int* in_sizes, int n_in,
                              void* d_out, int out_size, void* d_ws, size_t ws_size,
                              hipStream_t stream) {
    const float* Cf   = (const float*)d_in[0];
    const float* Sf   = (const float*)d_in[1];
    const float* temp = (const float*)d_in[2];

    const size_t MATEL = (size_t)B_N * D_K;            // 8M elems
    const size_t need  = MATEL * 2 * sizeof(unsigned short) + 3 * B_N * sizeof(float);

    dim3 grid(B_N / BM, B_N / BN);

    if (ws_size >= need) {
        unsigned short* Cb = (unsigned short*)d_ws;            // 16 MB
        unsigned short* Sb = Cb + MATEL;                       // 16 MB
        float* rowsum = (float*)(Sb + MATEL);                  // 16 KB
        float* colsum = rowsum + B_N;
        float* diag   = colsum + B_N;

        hipMemsetAsync(rowsum, 0, 2 * B_N * sizeof(float), stream);
        knorm2<<<2 * B_N, 256, 0, stream>>>(Cf, Sf, Cb, Sb);
        kgemm_bf<<<grid, 256, 0, stream>>>(Cb, Sb, temp, rowsum, colsum, diag);
        kfinal<<<1, 256, 0, stream>>>(rowsum, colsum, diag, temp, (float*)d_out);
    } else {
        float* ws     = (float*)d_ws;
        float* invc   = ws;
        float* invs   = ws + 4096;
        float* rowsum = ws + 8192;
        float* colsum = ws + 12288;
        float* diag   = ws + 16384;

        hipMemsetAsync(rowsum, 0, 2 * B_N * sizeof(float), stream);
        knorm<<<2 * B_N, 256, 0, stream>>>(Cf, Sf, invc, invs);
        kgemm_f32<<<grid, 256, 0, stream>>>(Cf, Sf, invc, invs, temp, rowsum, colsum, diag);
        kfinal<<<1, 256, 0, stream>>>(rowsum, colsum, diag, temp, (float*)d_out);
    }
}

// Round 3
// 97.631 us; speedup vs baseline: 1.8764x; 1.3317x over previous
//
#include <hip/hip_runtime.h>
#include <hip/hip_bf16.h>

#define B_N 4096
#define D_K 2048

typedef __attribute__((ext_vector_type(8))) short bf16x8;
typedef __attribute__((ext_vector_type(4))) float f32x4;

__device__ __forceinline__ unsigned short f2bf(float f) {
    union { __hip_bfloat16 h; unsigned short u; } cv;
    cv.h = __float2bfloat16(f);
    return cv.u;
}

__device__ __forceinline__ void gl_lds16(const unsigned short* g, unsigned short* l) {
    __builtin_amdgcn_global_load_lds(
        (const __attribute__((address_space(1))) unsigned int*)g,
        (__attribute__((address_space(3))) unsigned int*)l,
        16, 0, 0);
}

// ---------------- Kernel 1: row L2-normalize -> bf16 ----------------
__global__ __launch_bounds__(256) void knorm2(const float* __restrict__ C,
                                              const float* __restrict__ S,
                                              unsigned short* __restrict__ Cb,
                                              unsigned short* __restrict__ Sb) {
    int b = blockIdx.x;            // 0..8191
    const float* X;
    unsigned short* Y;
    if (b < B_N) { X = C + (size_t)b * D_K; Y = Cb + (size_t)b * D_K; }
    else         { X = S + (size_t)(b - B_N) * D_K; Y = Sb + (size_t)(b - B_N) * D_K; }
    int tid = threadIdx.x;

    float4 v0 = ((const float4*)X)[tid * 2];
    float4 v1 = ((const float4*)X)[tid * 2 + 1];
    float ss = v0.x*v0.x + v0.y*v0.y + v0.z*v0.z + v0.w*v0.w
             + v1.x*v1.x + v1.y*v1.y + v1.z*v1.z + v1.w*v1.w;
    #pragma unroll
    for (int off = 1; off < 64; off <<= 1) ss += __shfl_xor(ss, off, 64);
    __shared__ float wsum[4];
    if ((tid & 63) == 0) wsum[tid >> 6] = ss;
    __syncthreads();
    float tot = wsum[0] + wsum[1] + wsum[2] + wsum[3];
    float inv = 1.f / fmaxf(sqrtf(tot), 1e-12f);

    bf16x8 o;
    o[0] = (short)f2bf(v0.x * inv); o[1] = (short)f2bf(v0.y * inv);
    o[2] = (short)f2bf(v0.z * inv); o[3] = (short)f2bf(v0.w * inv);
    o[4] = (short)f2bf(v1.x * inv); o[5] = (short)f2bf(v1.y * inv);
    o[6] = (short)f2bf(v1.z * inv); o[7] = (short)f2bf(v1.w * inv);
    *(bf16x8*)(Y + tid * 8) = o;
}

// ---------------- Kernel 2: 256x256 8-phase GEMM + fused InfoNCE epilogue ----------------
// Tile 256x256, BK=64, 8 waves (2Mx4N), wave tile 128x64.
// LDS 128 KiB: [buf][ A-h0 | A-h1 | B-h0 | B-h1 ], each unit 16 KiB = [128 rows][64 cols] bf16,
// swizzled: 16B-chunk ^= (row&7)  (physical = logical ^ ((row&7)<<4) on byte offset).
// Units: A-h(q) = tile rows {wm*128 + q*64 .. +64} for wm=0,1 ; B-h(p) likewise with 32-row granules.
// Phase sequence per K-tile t (buffer c): Q(0,0) Q(0,1) Q(1,0) Q(1,1);
// stages: P0: B1(t+1)->c^1, P1: A1(t+1)->c^1, P2: A0(t+2)->c, P3: B0(t+2)->c ; vmcnt(4) at tile end.

#define BK 64
#define NT (D_K / BK)   /* 32 */

#define BARRIER()  asm volatile("s_barrier" ::: "memory")
#define LGKM0()    asm volatile("s_waitcnt lgkmcnt(0)" ::: "memory")
#define VMCNT4()   asm volatile("s_waitcnt vmcnt(4)" ::: "memory")

#define LDA_(boff, qm) do { _Pragma("unroll") \
  for (int mf = 0; mf < 4; ++mf) { \
    af[mf][0] = *(const bf16x8*)(ldsb + (boff) + (qm)*16384 + abase + mf*2048 + c0); \
    af[mf][1] = *(const bf16x8*)(ldsb + (boff) + (qm)*16384 + abase + mf*2048 + c1); \
  } } while (0)

#define LDB_(boff, qn) do { _Pragma("unroll") \
  for (int nf = 0; nf < 2; ++nf) { \
    bfr[qn][nf][0] = *(const bf16x8*)(ldsb + (boff) + 32768 + (qn)*16384 + bbase + nf*2048 + c0); \
    bfr[qn][nf][1] = *(const bf16x8*)(ldsb + (boff) + 32768 + (qn)*16384 + bbase + nf*2048 + c1); \
  } } while (0)

#define MMA_(qm, qn) do { _Pragma("unroll") \
  for (int mf = 0; mf < 4; ++mf) { _Pragma("unroll") \
    for (int nf = 0; nf < 2; ++nf) { \
      acc[(qm)*4+mf][(qn)*2+nf] = __builtin_amdgcn_mfma_f32_16x16x32_bf16(af[mf][0], bfr[qn][nf][0], acc[(qm)*4+mf][(qn)*2+nf], 0, 0, 0); \
      acc[(qm)*4+mf][(qn)*2+nf] = __builtin_amdgcn_mfma_f32_16x16x32_bf16(af[mf][1], bfr[qn][nf][1], acc[(qm)*4+mf][(qn)*2+nf], 0, 0, 0); \
    } } } while (0)

#define STAGE_A_(boff, q, kk) do { \
  gl_lds16(gA##q##0 + (kk), (unsigned short*)(ldsb + (boff) + (q)*16384 +        tid*16)); \
  gl_lds16(gA##q##1 + (kk), (unsigned short*)(ldsb + (boff) + (q)*16384 + 8192 + tid*16)); \
} while (0)

#define STAGE_B_(boff, p, kk) do { \
  gl_lds16(gB##p##0 + (kk), (unsigned short*)(ldsb + (boff) + 32768 + (p)*16384 +        tid*16)); \
  gl_lds16(gB##p##1 + (kk), (unsigned short*)(ldsb + (boff) + 32768 + (p)*16384 + 8192 + tid*16)); \
} while (0)

#define PHASE_SYNC(qm, qn) do { \
  BARRIER(); LGKM0(); __builtin_amdgcn_sched_barrier(0); \
  __builtin_amdgcn_s_setprio(1); MMA_(qm, qn); __builtin_amdgcn_s_setprio(0); \
} while (0)

__global__ __launch_bounds__(512, 2) void kgemm8(const unsigned short* __restrict__ Ab,
                                                 const unsigned short* __restrict__ Bb,
                                                 const float* __restrict__ temp,
                                                 float* __restrict__ rowsum,
                                                 float* __restrict__ colsum,
                                                 float* __restrict__ diag) {
    __shared__ __align__(128) char ldsb[131072];   // 128 KiB

    const int tid  = threadIdx.x;
    const int lane = tid & 63;
    const int wid  = tid >> 6;
    const int wm   = wid >> 2;     // 0..1
    const int wn   = wid & 3;      // 0..3

    // bijective XCD swizzle: 256 blocks = 8 XCDs x 32; 2 tile-rows per XCD
    int bid = blockIdx.x;
    int swz = (bid & 7) * 32 + (bid >> 3);
    int brow = (swz >> 4) * 256;
    int bcol = (swz & 15) * 256;

    // ---- staging constants (pre-swizzled global source, rule #21) ----
    const int rr = tid >> 3;                              // 0..63
    const int ch = (((tid & 7) ^ (rr & 7)) << 3);         // logical k-elem offset for this lane's chunk
    const unsigned short* gA00 = Ab + (size_t)(brow       + rr) * D_K + ch;             // q=0 j=0
    const unsigned short* gA01 = Ab + (size_t)(brow + 128 + rr) * D_K + ch;             // q=0 j=1
    const unsigned short* gA10 = Ab + (size_t)(brow +  64 + rr) * D_K + ch;             // q=1 j=0
    const unsigned short* gA11 = Ab + (size_t)(brow + 192 + rr) * D_K + ch;             // q=1 j=1
    const unsigned short* gB00 = Bb + (size_t)(bcol + ((rr>>5)    )*64      + (rr&31)) * D_K + ch;
    const unsigned short* gB01 = Bb + (size_t)(bcol + ((rr>>5) + 2)*64      + (rr&31)) * D_K + ch;
    const unsigned short* gB10 = Bb + (size_t)(bcol + ((rr>>5)    )*64 + 32 + (rr&31)) * D_K + ch;
    const unsigned short* gB11 = Bb + (size_t)(bcol + ((rr>>5) + 2)*64 + 32 + (rr&31)) * D_K + ch;

    // ---- ds_read constants (swizzled) ----
    const int lrow = lane & 15;
    const int kq   = lane >> 4;                 // 0..3
    const int sw   = (lane & 7) << 4;
    const int c0   = ((kq << 4)      ) ^ sw;    // ks=0 col bytes
    const int c1   = (64 | (kq << 4)) ^ sw;     // ks=1
    const int abase = (wm * 64 + lrow) * 128;
    const int bbase = (wn * 32 + lrow) * 128;

    const float scl = expf(temp[0]);

    f32x4 acc[8][4];
    #pragma unroll
    for (int i = 0; i < 8; ++i)
        #pragma unroll
        for (int j = 0; j < 4; ++j) acc[i][j] = (f32x4){0.f, 0.f, 0.f, 0.f};
    bf16x8 af[4][2];       // [mf][ks]
    bf16x8 bfr[2][2][2];   // [qn][nf][ks]

    // ---- prologue: tile0 all 4 units -> buf0; A0,B0 of tile1 -> buf1 ----
    STAGE_A_(0, 0, 0); STAGE_B_(0, 0, 0); STAGE_B_(0, 1, 0); STAGE_A_(0, 1, 0);
    STAGE_A_(65536, 0, BK); STAGE_B_(65536, 0, BK);
    VMCNT4();          // tile0 fully resident; A0/B0(1) may be in flight
    BARRIER();

    for (int t = 0; t < NT; ++t) {
        const int boff  = (t & 1) << 16;
        const int boffN = boff ^ 65536;
        const int k1 = (t + 1) * BK;
        const int k2 = (t + 2) * BK;
        const bool s1 = (t + 1 < NT);
        const bool s2 = (t + 2 < NT);

        // P0: Q(0,0) reads A0,B0
        LDA_(boff, 0); LDB_(boff, 0);
        if (s1) STAGE_B_(boffN, 1, k1);
        PHASE_SYNC(0, 0);
        BARRIER();
        // P1: Q(0,1) reads B1
        LDB_(boff, 1);
        if (s1) STAGE_A_(boffN, 1, k1);
        PHASE_SYNC(0, 1);
        BARRIER();
        // P2: Q(1,0) reads A1
        LDA_(boff, 1);
        if (s2) STAGE_A_(boff, 0, k2);
        PHASE_SYNC(1, 0);
        BARRIER();
        // P3: Q(1,1) no new ds_reads
        if (s2) STAGE_B_(boff, 0, k2);
        PHASE_SYNC(1, 1);
        VMCNT4();      // everything for tile t+1 resident; A0/B0(t+2) may fly
        BARRIER();
    }

    // ------- epilogue: relu*e^t, shifted exp, row/col partial sums, diag -------
    float cs[4] = {0.f, 0.f, 0.f, 0.f};
    #pragma unroll
    for (int mi = 0; mi < 8; ++mi) {
        float rs[4] = {0.f, 0.f, 0.f, 0.f};
        const int growb = brow + wm * 128 + (mi >> 2) * 64 + (mi & 3) * 16 + kq * 4;
        #pragma unroll
        for (int ni = 0; ni < 4; ++ni) {
            const int gc = bcol + wn * 64 + (ni >> 1) * 32 + (ni & 1) * 16 + lrow;
            #pragma unroll
            for (int j = 0; j < 4; ++j) {
                float v = fmaxf(acc[mi][ni][j], 0.f) * scl;
                if (growb + j == gc) diag[gc] = v;
                float p = expf(v - scl);
                rs[j]  += p;
                cs[ni] += p;
            }
        }
        #pragma unroll
        for (int j = 0; j < 4; ++j) {
            float v = rs[j];
            v += __shfl_xor(v, 1, 64);
            v += __shfl_xor(v, 2, 64);
            v += __shfl_xor(v, 4, 64);
            v += __shfl_xor(v, 8, 64);
            if (lrow == 0) atomicAdd(&rowsum[growb + j], v);
        }
    }
    #pragma unroll
    for (int ni = 0; ni < 4; ++ni) {
        float v = cs[ni];
        v += __shfl_xor(v, 16, 64);
        v += __shfl_xor(v, 32, 64);
        if (kq == 0) atomicAdd(&colsum[bcol + wn * 64 + (ni >> 1) * 32 + (ni & 1) * 16 + lrow], v);
    }
}

// ---------------- Kernel 3: final reduction to scalar loss ----------------
__global__ __launch_bounds__(256) void kfinal(const float* __restrict__ rowsum,
                                              const float* __restrict__ colsum,
                                              const float* __restrict__ diag,
                                              const float* __restrict__ temp,
                                              float* __restrict__ out) {
    int tid = threadIdx.x;
    float M = expf(temp[0]);
    float acc = 0.f;
    for (int i = tid; i < B_N; i += 256) {
        acc += logf(rowsum[i]) + logf(colsum[i]) + 2.f * M - 2.f * diag[i];
    }
    #pragma unroll
    for (int off = 1; off < 64; off <<= 1) acc += __shfl_xor(acc, off, 64);
    __shared__ float wsum[4];
    if ((tid & 63) == 0) wsum[tid >> 6] = acc;
    __syncthreads();
    if (tid == 0) {
        float t = wsum[0] + wsum[1] + wsum[2] + wsum[3];
        out[0] = t * (0.5f / (float)B_N);
    }
}

extern "C" void kernel_launch(void* const* d_in, const int* in_sizes, int n_in,
                              void* d_out, int out_size, void* d_ws, size_t ws_size,
                              hipStream_t stream) {
    const float* Cf   = (const float*)d_in[0];
    const float* Sf   = (const float*)d_in[1];
    const float* temp = (const float*)d_in[2];

    const size_t MATEL = (size_t)B_N * D_K;
    unsigned short* Cb = (unsigned short*)d_ws;            // 16 MB
    unsigned short* Sb = Cb + MATEL;                       // 16 MB
    float* rowsum = (float*)(Sb + MATEL);                  // 16 KB
    float* colsum = rowsum + B_N;
    float* diag   = colsum + B_N;

    hipMemsetAsync(rowsum, 0, 2 * B_N * sizeof(float), stream);
    knorm2<<<2 * B_N, 256, 0, stream>>>(Cf, Sf, Cb, Sb);
    kgemm8<<<256, 512, 0, stream>>>(Cb, Sb, temp, rowsum, colsum, diag);
    kfinal<<<1, 256, 0, stream>>>(rowsum, colsum, diag, temp, (float*)d_out);
}